// Round 10
// baseline (141.240 us; speedup 1.0000x reference)
//
#include <hip/hip_runtime.h>
#include <hip/hip_bf16.h>

typedef __bf16 bf16x8 __attribute__((ext_vector_type(8)));
typedef float f32x4 __attribute__((ext_vector_type(4)));

#define B_ 4
#define L_ 2048
#define D_ 512
#define H_ 8
#define QS 2048
#define SP 72

#define SB0 __builtin_amdgcn_sched_barrier(0)
#define WAIT_VM(n) asm volatile("s_waitcnt vmcnt(" #n ")" ::: "memory")
#define WAIT_LGKM0 asm volatile("s_waitcnt lgkmcnt(0)" ::: "memory")

// async 16B global -> LDS (gfx950 global_load_lds_dwordx4)
__device__ __forceinline__ void gl16(const __bf16* g, __bf16* l) {
  __builtin_amdgcn_global_load_lds(
      (const __attribute__((address_space(1))) void*)g,
      (__attribute__((address_space(3))) void*)l, 16, 0, 0);
}

// f32 -> bf16 WEIGHT conversion only (x is consumed f32 by gemm_qkvu now).
// vec8 regions: wqkv[0,98304) wu[98304,131072) wout[131072,163840)
// Also builds bcat[2048] = [b_qkv ; b_u] (f32) in block 0.
__global__ __launch_bounds__(256) void cvt_pack(
    const float* __restrict__ wq, const float* __restrict__ wu,
    const float* __restrict__ wo, const float* __restrict__ bq,
    const float* __restrict__ bu, __bf16* __restrict__ wcat,
    __bf16* __restrict__ wob, float* __restrict__ bcat)
{
  const int idx8 = blockIdx.x * 256 + threadIdx.x;
  const float* src; __bf16* dst; size_t so, dof;
  if (idx8 < 98304)       { src = wq; dst = wcat; so = (size_t)idx8 * 8;            dof = so; }
  else if (idx8 < 131072) { src = wu; dst = wcat; so = (size_t)(idx8 - 98304) * 8;  dof = so + 786432; }
  else                    { src = wo; dst = wob;  so = (size_t)(idx8 - 131072) * 8; dof = so; }
  const float4 lo = *(const float4*)(src + so);
  const float4 hi = *(const float4*)(src + so + 4);
  bf16x8 r;
  r[0] = (__bf16)lo.x; r[1] = (__bf16)lo.y; r[2] = (__bf16)lo.z; r[3] = (__bf16)lo.w;
  r[4] = (__bf16)hi.x; r[5] = (__bf16)hi.y; r[6] = (__bf16)hi.z; r[7] = (__bf16)hi.w;
  *(bf16x8*)(dst + dof) = r;
  if (blockIdx.x == 0) {
#pragma unroll
    for (int e = 0; e < 8; ++e) {
      const int col = threadIdx.x * 8 + e;
      bcat[col] = (col < 1536) ? bq[col] : bu[col - 1536];
    }
  }
}

// ---------------------------------------------------------------------------
// QKVU GEMM, 128x128 pipelined (r8/r9 schedule), A read DIRECTLY from x f32:
// qu[8192][2048] = x[8192][512](f32, cvt in-reg) @ wcat[2048][512]^T + bcat.
// A-staging is reg-staged (T14): f32 loads issued with stage(kt+2) (counted
// in vmcnt, 12 ops/tile -> entry vmcnt(12)); ds_write at the entry of the
// consuming tile (buf-p WAR guaranteed by the kt-2 barrier); lgkmcnt(0)
// before the entry barrier. Reg double-buffer ar0/ar1, STATIC indexing only
// (explicit pair-unrolled calls). (__bf16)(float) is the same rounding the
// old cvt_pack applied -> bit-identical xb values -> bit-identical output.
// Saves cvt's 25 MB x-traffic (~4 us) for ~+1.8 us in-gemm cost.
// ---------------------------------------------------------------------------
__global__ __launch_bounds__(256, 2) void gemm_qkvu(
    const float* __restrict__ X, const __bf16* __restrict__ W,
    const float* __restrict__ bias, __bf16* __restrict__ C)
{
  extern __shared__ char sm[];   // A: p*16384 (2x16K), B: 32768 + p*16384
  const int t = threadIdx.x;
  const int lane = t & 63;
  const int wave = t >> 6;
  const int wm = (wave >> 1) * 64;
  const int wn = (wave & 1) * 64;
  const int bm0 = blockIdx.x * 128;
  const int bn0 = blockIdx.y * 128;
  const int r = lane & 15, q = lane >> 4;
  const int N = 2048;            // K = 512, nt = 8

  auto stageA = [&](int kt, f32x4 (&ar)[8]) {
#pragma unroll
    for (int j = 0; j < 4; ++j) {
      const int c = t + j * 256;
      const int row = c >> 3;
      const int cs = (c & 7) ^ (row & 7);
      const float* src = X + (size_t)(bm0 + row) * 512 + kt * 64 + cs * 8;
      ar[2 * j]     = *(const f32x4*)src;
      ar[2 * j + 1] = *(const f32x4*)(src + 4);
    }
  };
  auto stageB = [&](int kt, int p) {
#pragma unroll
    for (int j = 0; j < 4; ++j) {
      const int c = t + j * 256;
      const int row = c >> 3;
      const int cs = (c & 7) ^ (row & 7);
      gl16(W + (size_t)(bn0 + row) * 512 + kt * 64 + cs * 8,
           (__bf16*)(sm + 32768 + p * 16384) + c * 8);
    }
  };
  auto writeA = [&](int p, f32x4 (&ar)[8]) {
#pragma unroll
    for (int j = 0; j < 4; ++j) {
      const int c = t + j * 256;
      bf16x8 v;
      v[0] = (__bf16)ar[2 * j][0];     v[1] = (__bf16)ar[2 * j][1];
      v[2] = (__bf16)ar[2 * j][2];     v[3] = (__bf16)ar[2 * j][3];
      v[4] = (__bf16)ar[2 * j + 1][0]; v[5] = (__bf16)ar[2 * j + 1][1];
      v[6] = (__bf16)ar[2 * j + 1][2]; v[7] = (__bf16)ar[2 * j + 1][3];
      *(bf16x8*)((__bf16*)(sm + p * 16384) + (size_t)c * 8) = v;
    }
  };
  auto rdA = [&](int p, int mi, int ks) -> bf16x8 {
    const int row = wm + mi * 16 + r;
    const int byte = row * 128 + ((ks * 64 + q * 16) ^ ((row & 7) << 4));
    return *(const bf16x8*)(sm + p * 16384 + byte);
  };
  auto rdB = [&](int p, int ni, int ks) -> bf16x8 {
    const int row = wn + ni * 16 + r;
    const int byte = row * 128 + ((ks * 64 + q * 16) ^ ((row & 7) << 4));
    return *(const bf16x8*)(sm + 32768 + p * 16384 + byte);
  };

  f32x4 acc[4][4] = {};
  f32x4 ar0[8], ar1[8];

  stageA(0, ar0); stageB(0, 0);
  stageA(1, ar1); stageB(1, 1);

  auto body = [&](int kt, f32x4 (&ar)[8]) {
    const int p = kt & 1;
    writeA(p, ar);               // compiler waits vmcnt for ar's loads
    WAIT_VM(12);                 // this tile's B gl16 landed (12 newer in flight)
    WAIT_LGKM0;                  // my A ds_writes retired
    SB0; __builtin_amdgcn_s_barrier(); SB0;

    bf16x8 a[4][2], b01[2][2], b23[2][2];
#pragma unroll
    for (int mi = 0; mi < 4; ++mi) { a[mi][0] = rdA(p, mi, 0); a[mi][1] = rdA(p, mi, 1); }
#pragma unroll
    for (int ni = 0; ni < 2; ++ni) { b01[ni][0] = rdB(p, ni, 0); b01[ni][1] = rdB(p, ni, 1); }
    __builtin_amdgcn_s_setprio(1);
#pragma unroll
    for (int mi = 0; mi < 4; ++mi)
#pragma unroll
      for (int ni = 0; ni < 2; ++ni) {
        acc[mi][ni] = __builtin_amdgcn_mfma_f32_16x16x32_bf16(a[mi][0], b01[ni][0], acc[mi][ni], 0, 0, 0);
        acc[mi][ni] = __builtin_amdgcn_mfma_f32_16x16x32_bf16(a[mi][1], b01[ni][1], acc[mi][ni], 0, 0, 0);
      }
    __builtin_amdgcn_s_setprio(0);
#pragma unroll
    for (int ni = 0; ni < 2; ++ni) { b23[ni][0] = rdB(p, ni + 2, 0); b23[ni][1] = rdB(p, ni + 2, 1); }
    WAIT_LGKM0;                  // all buf-p reads retired (WAR)
    SB0; __builtin_amdgcn_s_barrier(); SB0;
    if (kt + 2 < 8) { stageA(kt + 2, ar); stageB(kt + 2, p); }
    __builtin_amdgcn_s_setprio(1);
#pragma unroll
    for (int mi = 0; mi < 4; ++mi)
#pragma unroll
      for (int ni = 0; ni < 2; ++ni) {
        acc[mi][ni + 2] = __builtin_amdgcn_mfma_f32_16x16x32_bf16(a[mi][0], b23[ni][0], acc[mi][ni + 2], 0, 0, 0);
        acc[mi][ni + 2] = __builtin_amdgcn_mfma_f32_16x16x32_bf16(a[mi][1], b23[ni][1], acc[mi][ni + 2], 0, 0, 0);
      }
    __builtin_amdgcn_s_setprio(0);
  };

  // kt = 0..6 (pair-unrolled for static reg-buffer parity), peeled kt = 7
  body(0, ar0); body(1, ar1);
  body(2, ar0); body(3, ar1);
  body(4, ar0); body(5, ar1);
  body(6, ar0);

  // ---- peeled last tile (kt=7, p=1): C-stores interleaved with compute ----
  {
    const int p = 1;
    const int cc = lane & 15, cq = lane >> 4;
    writeA(p, ar1);
    WAIT_VM(0);
    WAIT_LGKM0;
    SB0; __builtin_amdgcn_s_barrier(); SB0;

    float bv[4];
#pragma unroll
    for (int ni = 0; ni < 4; ++ni) bv[ni] = bias[bn0 + wn + ni * 16 + cc];

    auto st = [&](int mi, int ni) {
      const int gcol = bn0 + wn + ni * 16 + cc;
#pragma unroll
      for (int rr = 0; rr < 4; ++rr) {
        const int grow = bm0 + wm + mi * 16 + cq * 4 + rr;
        C[(size_t)grow * N + gcol] = (__bf16)(acc[mi][ni][rr] + bv[ni]);
      }
    };

    bf16x8 a[4][2], b01[2][2], b23[2][2];
#pragma unroll
    for (int mi = 0; mi < 4; ++mi) { a[mi][0] = rdA(p, mi, 0); a[mi][1] = rdA(p, mi, 1); }
#pragma unroll
    for (int ni = 0; ni < 2; ++ni) { b01[ni][0] = rdB(p, ni, 0); b01[ni][1] = rdB(p, ni, 1); }
    __builtin_amdgcn_s_setprio(1);
#pragma unroll
    for (int mi = 0; mi < 4; ++mi)
#pragma unroll
      for (int ni = 0; ni < 2; ++ni) {
        acc[mi][ni] = __builtin_amdgcn_mfma_f32_16x16x32_bf16(a[mi][0], b01[ni][0], acc[mi][ni], 0, 0, 0);
        acc[mi][ni] = __builtin_amdgcn_mfma_f32_16x16x32_bf16(a[mi][1], b01[ni][1], acc[mi][ni], 0, 0, 0);
      }
    __builtin_amdgcn_s_setprio(0);
#pragma unroll
    for (int mi = 0; mi < 4; ++mi)
#pragma unroll
      for (int ni = 0; ni < 2; ++ni) st(mi, ni);          // half 0 out

#pragma unroll
    for (int ni = 0; ni < 2; ++ni) { b23[ni][0] = rdB(p, ni + 2, 0); b23[ni][1] = rdB(p, ni + 2, 1); }
    __builtin_amdgcn_s_setprio(1);
#pragma unroll
    for (int mi = 0; mi < 4; ++mi)
#pragma unroll
      for (int ni = 0; ni < 2; ++ni) {
        acc[mi][ni + 2] = __builtin_amdgcn_mfma_f32_16x16x32_bf16(a[mi][0], b23[ni][0], acc[mi][ni + 2], 0, 0, 0);
        acc[mi][ni + 2] = __builtin_amdgcn_mfma_f32_16x16x32_bf16(a[mi][1], b23[ni][1], acc[mi][ni + 2], 0, 0, 0);
      }
    __builtin_amdgcn_s_setprio(0);
#pragma unroll
    for (int mi = 0; mi < 4; ++mi)
#pragma unroll
      for (int ni = 2; ni < 4; ++ni) st(mi, ni);          // half 1 out
  }
}

// ---------------------------------------------------------------------------
// Out-proj GEMM: counted-vmcnt pipelined 64x128 tile, f32 out (r7 green).
// ---------------------------------------------------------------------------
__global__ __launch_bounds__(256, 2) void gemm_out(
    const __bf16* __restrict__ A, const __bf16* __restrict__ W,
    const float* __restrict__ bias, float* __restrict__ C)
{
  __shared__ char sm[49152];   // A: p*8192 (2x8K), B: 16384 + p*16384 (2x16K)
  const int t = threadIdx.x;
  const int lane = t & 63;
  const int wave = t >> 6;
  const int wm = (wave >> 1) * 32;
  const int wn = (wave & 1) * 64;
  const int bm0 = blockIdx.x * 64;
  const int bn0 = blockIdx.y * 128;
  const int r = lane & 15, q = lane >> 4;
  const int K = 512, N = 512;

  auto stage = [&](int kt, int p) {
#pragma unroll
    for (int j = 0; j < 2; ++j) {            // A: 512 chunks, 2/thread
      const int c = t + j * 256;
      const int row = c >> 3;
      const int cs = (c & 7) ^ (row & 7);
      gl16(A + (size_t)(bm0 + row) * K + kt * 64 + cs * 8,
           (__bf16*)(sm + p * 8192) + c * 8);
    }
#pragma unroll
    for (int j = 0; j < 4; ++j) {            // B: 1024 chunks, 4/thread
      const int c = t + j * 256;
      const int row = c >> 3;
      const int cs = (c & 7) ^ (row & 7);
      gl16(W + (size_t)(bn0 + row) * K + kt * 64 + cs * 8,
           (__bf16*)(sm + 16384 + p * 16384) + c * 8);
    }
  };
  auto rdA = [&](int p, int mi, int ks) -> bf16x8 {
    const int row = wm + mi * 16 + r;
    const int byte = row * 128 + ((ks * 64 + q * 16) ^ ((row & 7) << 4));
    return *(const bf16x8*)(sm + p * 8192 + byte);
  };
  auto rdB = [&](int p, int ni, int ks) -> bf16x8 {
    const int row = wn + ni * 16 + r;
    const int byte = row * 128 + ((ks * 64 + q * 16) ^ ((row & 7) << 4));
    return *(const bf16x8*)(sm + 16384 + p * 16384 + byte);
  };

  f32x4 acc[2][4] = {};
  stage(0, 0);
  stage(1, 1);

  for (int kt = 0; kt < 7; ++kt) {
    const int p = kt & 1;
    WAIT_VM(6);
    SB0; __builtin_amdgcn_s_barrier(); SB0;

    bf16x8 a[2][2], b01[2][2], b23[2][2];
#pragma unroll
    for (int mi = 0; mi < 2; ++mi) { a[mi][0] = rdA(p, mi, 0); a[mi][1] = rdA(p, mi, 1); }
#pragma unroll
    for (int ni = 0; ni < 2; ++ni) { b01[ni][0] = rdB(p, ni, 0); b01[ni][1] = rdB(p, ni, 1); }
    __builtin_amdgcn_s_setprio(1);
#pragma unroll
    for (int mi = 0; mi < 2; ++mi)
#pragma unroll
      for (int ni = 0; ni < 2; ++ni) {
        acc[mi][ni] = __builtin_amdgcn_mfma_f32_16x16x32_bf16(a[mi][0], b01[ni][0], acc[mi][ni], 0, 0, 0);
        acc[mi][ni] = __builtin_amdgcn_mfma_f32_16x16x32_bf16(a[mi][1], b01[ni][1], acc[mi][ni], 0, 0, 0);
      }
    __builtin_amdgcn_s_setprio(0);
#pragma unroll
    for (int ni = 0; ni < 2; ++ni) { b23[ni][0] = rdB(p, ni + 2, 0); b23[ni][1] = rdB(p, ni + 2, 1); }
    WAIT_LGKM0;                 // all buf-p reads retired
    SB0; __builtin_amdgcn_s_barrier(); SB0;
    if (kt + 2 < 8) stage(kt + 2, p);
    __builtin_amdgcn_s_setprio(1);
#pragma unroll
    for (int mi = 0; mi < 2; ++mi)
#pragma unroll
      for (int ni = 0; ni < 2; ++ni) {
        acc[mi][ni + 2] = __builtin_amdgcn_mfma_f32_16x16x32_bf16(a[mi][0], b23[ni][0], acc[mi][ni + 2], 0, 0, 0);
        acc[mi][ni + 2] = __builtin_amdgcn_mfma_f32_16x16x32_bf16(a[mi][1], b23[ni][1], acc[mi][ni + 2], 0, 0, 0);
      }
    __builtin_amdgcn_s_setprio(0);
  }

  // ---- peeled last tile (kt=7, p=1): stores interleaved ----
  {
    const int p = 1;
    const int cc = lane & 15, cq = lane >> 4;
    WAIT_VM(0);
    SB0; __builtin_amdgcn_s_barrier(); SB0;

    float bv[4];
#pragma unroll
    for (int ni = 0; ni < 4; ++ni) bv[ni] = bias[bn0 + wn + ni * 16 + cc];

    auto st = [&](int mi, int ni) {
      const int gcol = bn0 + wn + ni * 16 + cc;
#pragma unroll
      for (int rr = 0; rr < 4; ++rr) {
        const int grow = bm0 + wm + mi * 16 + cq * 4 + rr;
        C[(size_t)grow * N + gcol] = acc[mi][ni][rr] + bv[ni];
      }
    };

    bf16x8 a[2][2], b01[2][2], b23[2][2];
#pragma unroll
    for (int mi = 0; mi < 2; ++mi) { a[mi][0] = rdA(p, mi, 0); a[mi][1] = rdA(p, mi, 1); }
#pragma unroll
    for (int ni = 0; ni < 2; ++ni) { b01[ni][0] = rdB(p, ni, 0); b01[ni][1] = rdB(p, ni, 1); }
    __builtin_amdgcn_s_setprio(1);
#pragma unroll
    for (int mi = 0; mi < 2; ++mi)
#pragma unroll
      for (int ni = 0; ni < 2; ++ni) {
        acc[mi][ni] = __builtin_amdgcn_mfma_f32_16x16x32_bf16(a[mi][0], b01[ni][0], acc[mi][ni], 0, 0, 0);
        acc[mi][ni] = __builtin_amdgcn_mfma_f32_16x16x32_bf16(a[mi][1], b01[ni][1], acc[mi][ni], 0, 0, 0);
      }
    __builtin_amdgcn_s_setprio(0);
#pragma unroll
    for (int mi = 0; mi < 2; ++mi)
#pragma unroll
      for (int ni = 0; ni < 2; ++ni) st(mi, ni);          // half 0 out

#pragma unroll
    for (int ni = 0; ni < 2; ++ni) { b23[ni][0] = rdB(p, ni + 2, 0); b23[ni][1] = rdB(p, ni + 2, 1); }
    __builtin_amdgcn_s_setprio(1);
#pragma unroll
    for (int mi = 0; mi < 2; ++mi)
#pragma unroll
      for (int ni = 0; ni < 2; ++ni) {
        acc[mi][ni + 2] = __builtin_amdgcn_mfma_f32_16x16x32_bf16(a[mi][0], b23[ni][0], acc[mi][ni + 2], 0, 0, 0);
        acc[mi][ni + 2] = __builtin_amdgcn_mfma_f32_16x16x32_bf16(a[mi][1], b23[ni][1], acc[mi][ni + 2], 0, 0, 0);
      }
    __builtin_amdgcn_s_setprio(0);
#pragma unroll
    for (int mi = 0; mi < 2; ++mi)
#pragma unroll
      for (int ni = 2; ni < 4; ++ni) st(mi, ni);          // half 1 out
  }
}

// Flash-style MFMA attention, QBLK=128 / 512 threads / 8 waves (r9 green).
__global__ __launch_bounds__(512) void attn_tile(
    const __bf16* __restrict__ qu,   // [B*L][2048]  q|k|v|u
    __bf16* __restrict__ g)          // [B*L][512]
{
  const int qt = blockIdx.x, h = blockIdx.y, b = blockIdx.z;
  const int t = threadIdx.x;
  const int lane = t & 63;
  const int w = t >> 6;                    // 8 waves, 16 q-rows each
  const int q0 = qt * 128, qmax = q0 + 127;
  const size_t bL = (size_t)b * L_;

  __shared__ __bf16 lK[4096];        // [64][64] bf16, XOR-swizzled rows (8KB)
  __shared__ __bf16 lV[64 * SP];     // V^T: [d 64][key 64] stride 72 (9KB)
  __shared__ __bf16 Pb[128 * SP];    // P: [q 128][key 64] stride 72 (18KB)

  const int cq = lane >> 4, cc = lane & 15;
  const int krow_st = t >> 3, kgb8 = t & 7;   // K-staging: 64 rows x 8 chunks

  // Q fragments, pre-scaled by 1/sqrt(HD)=0.125 (exact pow2 scale)
  bf16x8 aq0, aq1;
  {
    const __bf16* qsrc = qu + (bL + q0 + w * 16 + cc) * QS + h * 64 + cq * 8;
    bf16x8 t0 = *(const bf16x8*)qsrc;
    bf16x8 t1 = *(const bf16x8*)(qsrc + 32);
#pragma unroll
    for (int e = 0; e < 8; ++e) {
      aq0[e] = (__bf16)((float)t0[e] * 0.125f);
      aq1[e] = (__bf16)((float)t1[e] * 0.125f);
    }
  }

  float mreg[4], lreg[4];
#pragma unroll
  for (int rr = 0; rr < 4; ++rr) { mreg[rr] = -1e30f; lreg[rr] = 0.f; }
  f32x4 acc_o[4] = {};

  int clist[8]; int ncl = 0;
  clist[ncl++] = 0;
  if (qmax >= 64) clist[ncl++] = 64;
  {
    int lo = 1984 - qmax; if (lo < 0) lo = 0; lo &= ~63;
    const int hik = min(qmax, 2048 - q0);
    for (int c = lo; c <= hik; c += 64)
      if (c >= 128) clist[ncl++] = c;
  }

  // prologue: tile-0 K/V into registers (T14 pipeline)
  bf16x8 k0r, var;
  {
    const __bf16* src = qu + (bL + clist[0] + krow_st) * QS + 512 + h * 64;
    k0r = *(const bf16x8*)(src + kgb8 * 8);
    const __bf16* vsrc = qu + (bL + clist[0] + lane) * QS + 1024 + h * 64 + w * 8;
    var = *(const bf16x8*)vsrc;
  }

  for (int ci = 0; ci < ncl; ++ci) {
    const int c0 = clist[ci];
    // block-uniform tile classification
    const bool thin = (c0 == 64) && (qmax <= 1856);   // only col j=64 valid
    const bool fast0 = (c0 == 0) && (q0 >= 64) && (qmax + 63 <= 2048);

    WAIT_VM(0);                                 // this tile's K/V landed
    SB0; __builtin_amdgcn_s_barrier(); SB0;     // WAR: prior tile's reads done
    {
      char* lkb = (char*)lK;
      const int sw = (krow_st & 7) << 4;
      *(bf16x8*)(lkb + ((krow_st * 128 + kgb8 * 16) ^ sw)) = k0r;
#pragma unroll
      for (int e = 0; e < 8; ++e)
        lV[(w * 8 + e) * SP + lane] = var[e];
    }
    if (ci + 1 < ncl) {                         // issue next tile's loads
      const int cn = clist[ci + 1];
      const __bf16* src = qu + (bL + cn + krow_st) * QS + 512 + h * 64;
      k0r = *(const bf16x8*)(src + kgb8 * 8);
      const __bf16* vsrc = qu + (bL + cn + lane) * QS + 1024 + h * 64 + w * 8;
      var = *(const bf16x8*)vsrc;
    }
    WAIT_LGKM0;                                 // my ds_writes retired
    SB0; __builtin_amdgcn_s_barrier(); SB0;     // RAW: all writes visible

    // QK^T (nt=0 only on thin tiles)
    f32x4 s[4];
    {
      const char* lkb = (const char*)lK;
      auto qk = [&](int nt) {
        const int krow = nt * 16 + cc;
        const int sw = (krow & 7) << 4;
        bf16x8 bk0 = *(const bf16x8*)(lkb + ((krow * 128 + cq * 16) ^ sw));
        bf16x8 bk1 = *(const bf16x8*)(lkb + ((krow * 128 + 64 + cq * 16) ^ sw));
        f32x4 a = {};
        a = __builtin_amdgcn_mfma_f32_16x16x32_bf16(aq0, bk0, a, 0, 0, 0);
        a = __builtin_amdgcn_mfma_f32_16x16x32_bf16(aq1, bk1, a, 0, 0, 0);
        s[nt] = a;
      };
      qk(0);
      if (!thin) { qk(1); qk(2); qk(3); }
    }

    // mask (Q pre-scaled; no *0.125 here)
    if (!fast0) {
      const int ntm = thin ? 1 : 4;
      if (c0 >= 128) {
        // band-only mask: glob (j<=64) impossible here
        for (int nt = 0; nt < 4; ++nt) {
          if (nt >= ntm) break;
#pragma unroll
          for (int rr = 0; rr < 4; ++rr) {
            const int i = q0 + w * 16 + cq * 4 + rr;
            const int j = c0 + nt * 16 + cc;
            const int ij = i + j;
            const bool valid = (j <= i) && (ij >= 1984) && (ij <= 2048);
            s[nt][rr] = valid ? s[nt][rr] : -1e30f;
          }
        }
      } else {
        for (int nt = 0; nt < 4; ++nt) {
          if (nt >= ntm) break;
#pragma unroll
          for (int rr = 0; rr < 4; ++rr) {
            const int i = q0 + w * 16 + cq * 4 + rr;
            const int j = c0 + nt * 16 + cc;
            const int ij = i + j;
            const bool valid = (j <= i) &&
                ((ij >= 1984 && ij <= 2048) || (j <= 64 && ij <= 2048));
            s[nt][rr] = valid ? s[nt][rr] : -1e30f;
          }
        }
      }
    }

    // row max (in-lane over active nt, then 16-lane shfl tree)
    f32x4 pm;
#pragma unroll
    for (int rr = 0; rr < 4; ++rr) pm[rr] = s[0][rr];
    if (!thin) {
#pragma unroll
      for (int rr = 0; rr < 4; ++rr)
        pm[rr] = fmaxf(fmaxf(pm[rr], s[1][rr]), fmaxf(s[2][rr], s[3][rr]));
    }
#pragma unroll
    for (int m = 1; m < 16; m <<= 1) {
#pragma unroll
      for (int rr = 0; rr < 4; ++rr)
        pm[rr] = fmaxf(pm[rr], __shfl_xor(pm[rr], m, 64));
    }
    float corr[4];
#pragma unroll
    for (int rr = 0; rr < 4; ++rr) {
      const float nm = fmaxf(mreg[rr], pm[rr]);
      corr[rr] = __expf(mreg[rr] - nm);
      mreg[rr] = nm;
    }

    // P = exp(s - m); thin: write nt=0, zero slots 16..31 (PV k<=31 reads)
    f32x4 ps = {};
    if (thin) {
#pragma unroll
      for (int rr = 0; rr < 4; ++rr) {
        const float p = __expf(s[0][rr] - mreg[rr]);
        ps[rr] += p;
        const int prow = (w * 16 + cq * 4 + rr) * SP;
        Pb[prow + cc] = (__bf16)p;
        Pb[prow + 16 + cc] = (__bf16)0.f;
      }
    } else {
#pragma unroll
      for (int nt = 0; nt < 4; ++nt) {
#pragma unroll
        for (int rr = 0; rr < 4; ++rr) {
          const float p = __expf(s[nt][rr] - mreg[rr]);
          ps[rr] += p;
          Pb[(w * 16 + cq * 4 + rr) * SP + nt * 16 + cc] = (__bf16)p;
        }
      }
    }
#pragma unroll
    for (int m = 1; m < 16; m <<= 1) {
#pragma unroll
      for (int rr = 0; rr < 4; ++rr)
        ps[rr] += __shfl_xor(ps[rr], m, 64);
    }
#pragma unroll
    for (int rr = 0; rr < 4; ++rr) lreg[rr] = lreg[rr] * corr[rr] + ps[rr];

    // PV (thin: k=0..31 half only -> 4 MFMA)
    {
      bf16x8 pa0 = *(const bf16x8*)(Pb + (w * 16 + cc) * SP + cq * 8);
      if (thin) {
#pragma unroll
        for (int dt = 0; dt < 4; ++dt) {
#pragma unroll
          for (int rr = 0; rr < 4; ++rr) acc_o[dt][rr] *= corr[rr];
          bf16x8 vb0 = *(const bf16x8*)(lV + (dt * 16 + cc) * SP + cq * 8);
          acc_o[dt] = __builtin_amdgcn_mfma_f32_16x16x32_bf16(pa0, vb0, acc_o[dt], 0, 0, 0);
        }
      } else {
        bf16x8 pa1 = *(const bf16x8*)(Pb + (w * 16 + cc) * SP + 32 + cq * 8);
#pragma unroll
        for (int dt = 0; dt < 4; ++dt) {
#pragma unroll
          for (int rr = 0; rr < 4; ++rr) acc_o[dt][rr] *= corr[rr];
          bf16x8 vb0 = *(const bf16x8*)(lV + (dt * 16 + cc) * SP + cq * 8);
          bf16x8 vb1 = *(const bf16x8*)(lV + (dt * 16 + cc) * SP + 32 + cq * 8);
          acc_o[dt] = __builtin_amdgcn_mfma_f32_16x16x32_bf16(pa0, vb0, acc_o[dt], 0, 0, 0);
          acc_o[dt] = __builtin_amdgcn_mfma_f32_16x16x32_bf16(pa1, vb1, acc_o[dt], 0, 0, 0);
        }
      }
    }
  }

  // epilogue: register state only
#pragma unroll
  for (int dt = 0; dt < 4; ++dt) {
#pragma unroll
    for (int rr = 0; rr < 4; ++rr) {
      const int row16 = cq * 4 + rr;
      const size_t qrow = bL + q0 + w * 16 + row16;
      const int d = dt * 16 + cc;
      const float o = acc_o[dt][rr] / fmaxf(lreg[rr], 1e-30f);
      const float uv = (float)qu[qrow * QS + 1536 + h * 64 + d];
      g[qrow * D_ + h * 64 + d] = (__bf16)(o / (1.f + __expf(-o)) * uv);
    }
  }
}

extern "C" void kernel_launch(void* const* d_in, const int* in_sizes, int n_in,
                              void* d_out, int out_size, void* d_ws, size_t ws_size,
                              hipStream_t stream) {
  const float* x     = (const float*)d_in[0];
  const float* w_qkv = (const float*)d_in[1];
  const float* b_qkv = (const float*)d_in[2];
  const float* w_u   = (const float*)d_in[3];
  const float* b_u   = (const float*)d_in[4];
  const float* w_out = (const float*)d_in[5];
  const float* b_out = (const float*)d_in[6];
  float* out = (float*)d_out;

  char* ws = (char*)d_ws;
  __bf16* wcat = (__bf16*)ws;                           //  2 MB [w_qkv;w_u]
  __bf16* wob  = (__bf16*)(ws + 2097152);               //  0.5 MB
  float*  bcat = (float*) (ws + 2621440);               //  8 KB
  __bf16* qu   = (__bf16*)(ws + 2629632);               // 32 MB [q|k|v|u]
  __bf16* gb   = (__bf16*)(ws + 36184064);              //  8 MB

  // one-time opt-in for 64 KB dynamic LDS (host-side attr, graph-safe)
  static bool attr_done = []() {
    hipFuncSetAttribute((const void*)gemm_qkvu,
                        hipFuncAttributeMaxDynamicSharedMemorySize, 65536);
    return true;
  }();
  (void)attr_done;

  cvt_pack<<<dim3(640), dim3(256), 0, stream>>>(
      w_qkv, w_u, w_out, b_qkv, b_u, wcat, wob, bcat);
  gemm_qkvu<<<dim3(64, 16), dim3(256), 65536, stream>>>(
      x, wcat, bcat, qu);
  attn_tile<<<dim3(L_ / 128, H_, B_), dim3(512), 0, stream>>>(qu, gb);
  gemm_out<<<dim3(128, 4), dim3(256), 0, stream>>>(
      gb, wob, b_out, out);
}

// Round 11
// 138.009 us; speedup vs baseline: 1.0234x; 1.0234x over previous
//
#include <hip/hip_runtime.h>
#include <hip/hip_bf16.h>

typedef __bf16 bf16x8 __attribute__((ext_vector_type(8)));
typedef float f32x4 __attribute__((ext_vector_type(4)));

#define B_ 4
#define L_ 2048
#define D_ 512
#define H_ 8
#define QS 2048
#define SP 72

#define SB0 __builtin_amdgcn_sched_barrier(0)
#define WAIT_VM(n) asm volatile("s_waitcnt vmcnt(" #n ")" ::: "memory")
#define WAIT_LGKM0 asm volatile("s_waitcnt lgkmcnt(0)" ::: "memory")

// async 16B global -> LDS (gfx950 global_load_lds_dwordx4)
__device__ __forceinline__ void gl16(const __bf16* g, __bf16* l) {
  __builtin_amdgcn_global_load_lds(
      (const __attribute__((address_space(1))) void*)g,
      (__attribute__((address_space(3))) void*)l, 16, 0, 0);
}

// f32 -> bf16 conversion + packing. vec8 regions:
// x[0,524288) wqkv[524288,622592) wu[622592,655360) wout[655360,688128)
// Also builds bcat[2048] = [b_qkv ; b_u] (f32) in block 0.
__global__ __launch_bounds__(256) void cvt_pack(
    const float* __restrict__ x, const float* __restrict__ wq,
    const float* __restrict__ wu, const float* __restrict__ wo,
    const float* __restrict__ bq, const float* __restrict__ bu,
    __bf16* __restrict__ xb, __bf16* __restrict__ wcat,
    __bf16* __restrict__ wob, float* __restrict__ bcat)
{
  const int idx8 = blockIdx.x * 256 + threadIdx.x;
  const float* src; __bf16* dst; size_t so, dof;
  if (idx8 < 524288)      { src = x;  dst = xb;   so = (size_t)idx8 * 8;            dof = so; }
  else if (idx8 < 622592) { src = wq; dst = wcat; so = (size_t)(idx8 - 524288) * 8; dof = so; }
  else if (idx8 < 655360) { src = wu; dst = wcat; so = (size_t)(idx8 - 622592) * 8; dof = so + 786432; }
  else                    { src = wo; dst = wob;  so = (size_t)(idx8 - 655360) * 8; dof = so; }
  const float4 lo = *(const float4*)(src + so);
  const float4 hi = *(const float4*)(src + so + 4);
  bf16x8 r;
  r[0] = (__bf16)lo.x; r[1] = (__bf16)lo.y; r[2] = (__bf16)lo.z; r[3] = (__bf16)lo.w;
  r[4] = (__bf16)hi.x; r[5] = (__bf16)hi.y; r[6] = (__bf16)hi.z; r[7] = (__bf16)hi.w;
  *(bf16x8*)(dst + dof) = r;
  if (blockIdx.x == 0) {
#pragma unroll
    for (int e = 0; e < 8; ++e) {
      const int col = threadIdx.x * 8 + e;
      bcat[col] = (col < 1536) ? bq[col] : bu[col - 1536];
    }
  }
}

// ---------------------------------------------------------------------------
// QKVU GEMM: counted-vmcnt pipelined 128x128 tile, bf16 out (r8/r9 green).
// ---------------------------------------------------------------------------
__global__ __launch_bounds__(256, 2) void gemm128(
    const __bf16* __restrict__ A, const __bf16* __restrict__ W,
    const float* __restrict__ bias, __bf16* __restrict__ C,
    int M, int N, int K)
{
  extern __shared__ char sm[];   // A: p*16384 (2x16K), B: 32768 + p*16384
  const int t = threadIdx.x;
  const int lane = t & 63;
  const int wave = t >> 6;
  const int wm = (wave >> 1) * 64;
  const int wn = (wave & 1) * 64;
  const int bm0 = blockIdx.x * 128;
  const int bn0 = blockIdx.y * 128;
  const int r = lane & 15, q = lane >> 4;
  const int nt = K >> 6;

  auto stage = [&](int kt, int p) {
#pragma unroll
    for (int j = 0; j < 4; ++j) {            // A: 1024 chunks, 4/thread
      const int c = t + j * 256;
      const int row = c >> 3;
      const int cs = (c & 7) ^ (row & 7);
      gl16(A + (size_t)(bm0 + row) * K + kt * 64 + cs * 8,
           (__bf16*)(sm + p * 16384) + c * 8);
    }
#pragma unroll
    for (int j = 0; j < 4; ++j) {            // B: 1024 chunks, 4/thread
      const int c = t + j * 256;
      const int row = c >> 3;
      const int cs = (c & 7) ^ (row & 7);
      gl16(W + (size_t)(bn0 + row) * K + kt * 64 + cs * 8,
           (__bf16*)(sm + 32768 + p * 16384) + c * 8);
    }
  };
  auto rdA = [&](int p, int mi, int ks) -> bf16x8 {
    const int row = wm + mi * 16 + r;
    const int byte = row * 128 + ((ks * 64 + q * 16) ^ ((row & 7) << 4));
    return *(const bf16x8*)(sm + p * 16384 + byte);
  };
  auto rdB = [&](int p, int ni, int ks) -> bf16x8 {
    const int row = wn + ni * 16 + r;
    const int byte = row * 128 + ((ks * 64 + q * 16) ^ ((row & 7) << 4));
    return *(const bf16x8*)(sm + 32768 + p * 16384 + byte);
  };

  f32x4 acc[4][4] = {};
  stage(0, 0);
  stage(1, 1);

  for (int kt = 0; kt < nt - 1; ++kt) {
    const int p = kt & 1;
    WAIT_VM(8);
    SB0; __builtin_amdgcn_s_barrier(); SB0;

    bf16x8 a[4][2], b01[2][2], b23[2][2];
#pragma unroll
    for (int mi = 0; mi < 4; ++mi) { a[mi][0] = rdA(p, mi, 0); a[mi][1] = rdA(p, mi, 1); }
#pragma unroll
    for (int ni = 0; ni < 2; ++ni) { b01[ni][0] = rdB(p, ni, 0); b01[ni][1] = rdB(p, ni, 1); }
    __builtin_amdgcn_s_setprio(1);
#pragma unroll
    for (int mi = 0; mi < 4; ++mi)
#pragma unroll
      for (int ni = 0; ni < 2; ++ni) {
        acc[mi][ni] = __builtin_amdgcn_mfma_f32_16x16x32_bf16(a[mi][0], b01[ni][0], acc[mi][ni], 0, 0, 0);
        acc[mi][ni] = __builtin_amdgcn_mfma_f32_16x16x32_bf16(a[mi][1], b01[ni][1], acc[mi][ni], 0, 0, 0);
      }
    __builtin_amdgcn_s_setprio(0);
#pragma unroll
    for (int ni = 0; ni < 2; ++ni) { b23[ni][0] = rdB(p, ni + 2, 0); b23[ni][1] = rdB(p, ni + 2, 1); }
    WAIT_LGKM0;                 // all buf-p reads retired (WAR)
    SB0; __builtin_amdgcn_s_barrier(); SB0;
    if (kt + 2 < nt) stage(kt + 2, p);
    __builtin_amdgcn_s_setprio(1);
#pragma unroll
    for (int mi = 0; mi < 4; ++mi)
#pragma unroll
      for (int ni = 0; ni < 2; ++ni) {
        acc[mi][ni + 2] = __builtin_amdgcn_mfma_f32_16x16x32_bf16(a[mi][0], b23[ni][0], acc[mi][ni + 2], 0, 0, 0);
        acc[mi][ni + 2] = __builtin_amdgcn_mfma_f32_16x16x32_bf16(a[mi][1], b23[ni][1], acc[mi][ni + 2], 0, 0, 0);
      }
    __builtin_amdgcn_s_setprio(0);
  }

  // ---- peeled last tile: interleave C-stores with remaining compute ----
  {
    const int p = (nt - 1) & 1;
    const int cc = lane & 15, cq = lane >> 4;
    WAIT_VM(0);
    SB0; __builtin_amdgcn_s_barrier(); SB0;

    float bv[4];
#pragma unroll
    for (int ni = 0; ni < 4; ++ni) bv[ni] = bias[bn0 + wn + ni * 16 + cc];

    auto st = [&](int mi, int ni) {
      const int gcol = bn0 + wn + ni * 16 + cc;
#pragma unroll
      for (int rr = 0; rr < 4; ++rr) {
        const int grow = bm0 + wm + mi * 16 + cq * 4 + rr;
        C[(size_t)grow * N + gcol] = (__bf16)(acc[mi][ni][rr] + bv[ni]);
      }
    };

    bf16x8 a[4][2], b01[2][2], b23[2][2];
#pragma unroll
    for (int mi = 0; mi < 4; ++mi) { a[mi][0] = rdA(p, mi, 0); a[mi][1] = rdA(p, mi, 1); }
#pragma unroll
    for (int ni = 0; ni < 2; ++ni) { b01[ni][0] = rdB(p, ni, 0); b01[ni][1] = rdB(p, ni, 1); }
    __builtin_amdgcn_s_setprio(1);
#pragma unroll
    for (int mi = 0; mi < 4; ++mi)
#pragma unroll
      for (int ni = 0; ni < 2; ++ni) {
        acc[mi][ni] = __builtin_amdgcn_mfma_f32_16x16x32_bf16(a[mi][0], b01[ni][0], acc[mi][ni], 0, 0, 0);
        acc[mi][ni] = __builtin_amdgcn_mfma_f32_16x16x32_bf16(a[mi][1], b01[ni][1], acc[mi][ni], 0, 0, 0);
      }
    __builtin_amdgcn_s_setprio(0);
#pragma unroll
    for (int mi = 0; mi < 4; ++mi)
#pragma unroll
      for (int ni = 0; ni < 2; ++ni) st(mi, ni);          // half 0 out

#pragma unroll
    for (int ni = 0; ni < 2; ++ni) { b23[ni][0] = rdB(p, ni + 2, 0); b23[ni][1] = rdB(p, ni + 2, 1); }
    __builtin_amdgcn_s_setprio(1);
#pragma unroll
    for (int mi = 0; mi < 4; ++mi)
#pragma unroll
      for (int ni = 0; ni < 2; ++ni) {
        acc[mi][ni + 2] = __builtin_amdgcn_mfma_f32_16x16x32_bf16(a[mi][0], b23[ni][0], acc[mi][ni + 2], 0, 0, 0);
        acc[mi][ni + 2] = __builtin_amdgcn_mfma_f32_16x16x32_bf16(a[mi][1], b23[ni][1], acc[mi][ni + 2], 0, 0, 0);
      }
    __builtin_amdgcn_s_setprio(0);
#pragma unroll
    for (int mi = 0; mi < 4; ++mi)
#pragma unroll
      for (int ni = 2; ni < 4; ++ni) st(mi, ni);          // half 1 out
  }
}

// ---------------------------------------------------------------------------
// Out-proj GEMM: counted-vmcnt pipelined 64x128 tile, f32 out (r7 green).
// ---------------------------------------------------------------------------
__global__ __launch_bounds__(256, 2) void gemm_out(
    const __bf16* __restrict__ A, const __bf16* __restrict__ W,
    const float* __restrict__ bias, float* __restrict__ C)
{
  __shared__ char sm[49152];   // A: p*8192 (2x8K), B: 16384 + p*16384 (2x16K)
  const int t = threadIdx.x;
  const int lane = t & 63;
  const int wave = t >> 6;
  const int wm = (wave >> 1) * 32;
  const int wn = (wave & 1) * 64;
  const int bm0 = blockIdx.x * 64;
  const int bn0 = blockIdx.y * 128;
  const int r = lane & 15, q = lane >> 4;
  const int K = 512, N = 512;

  auto stage = [&](int kt, int p) {
#pragma unroll
    for (int j = 0; j < 2; ++j) {            // A: 512 chunks, 2/thread
      const int c = t + j * 256;
      const int row = c >> 3;
      const int cs = (c & 7) ^ (row & 7);
      gl16(A + (size_t)(bm0 + row) * K + kt * 64 + cs * 8,
           (__bf16*)(sm + p * 8192) + c * 8);
    }
#pragma unroll
    for (int j = 0; j < 4; ++j) {            // B: 1024 chunks, 4/thread
      const int c = t + j * 256;
      const int row = c >> 3;
      const int cs = (c & 7) ^ (row & 7);
      gl16(W + (size_t)(bn0 + row) * K + kt * 64 + cs * 8,
           (__bf16*)(sm + 16384 + p * 16384) + c * 8);
    }
  };
  auto rdA = [&](int p, int mi, int ks) -> bf16x8 {
    const int row = wm + mi * 16 + r;
    const int byte = row * 128 + ((ks * 64 + q * 16) ^ ((row & 7) << 4));
    return *(const bf16x8*)(sm + p * 8192 + byte);
  };
  auto rdB = [&](int p, int ni, int ks) -> bf16x8 {
    const int row = wn + ni * 16 + r;
    const int byte = row * 128 + ((ks * 64 + q * 16) ^ ((row & 7) << 4));
    return *(const bf16x8*)(sm + 16384 + p * 16384 + byte);
  };

  f32x4 acc[2][4] = {};
  stage(0, 0);
  stage(1, 1);

  for (int kt = 0; kt < 7; ++kt) {
    const int p = kt & 1;
    WAIT_VM(6);
    SB0; __builtin_amdgcn_s_barrier(); SB0;

    bf16x8 a[2][2], b01[2][2], b23[2][2];
#pragma unroll
    for (int mi = 0; mi < 2; ++mi) { a[mi][0] = rdA(p, mi, 0); a[mi][1] = rdA(p, mi, 1); }
#pragma unroll
    for (int ni = 0; ni < 2; ++ni) { b01[ni][0] = rdB(p, ni, 0); b01[ni][1] = rdB(p, ni, 1); }
    __builtin_amdgcn_s_setprio(1);
#pragma unroll
    for (int mi = 0; mi < 2; ++mi)
#pragma unroll
      for (int ni = 0; ni < 2; ++ni) {
        acc[mi][ni] = __builtin_amdgcn_mfma_f32_16x16x32_bf16(a[mi][0], b01[ni][0], acc[mi][ni], 0, 0, 0);
        acc[mi][ni] = __builtin_amdgcn_mfma_f32_16x16x32_bf16(a[mi][1], b01[ni][1], acc[mi][ni], 0, 0, 0);
      }
    __builtin_amdgcn_s_setprio(0);
#pragma unroll
    for (int ni = 0; ni < 2; ++ni) { b23[ni][0] = rdB(p, ni + 2, 0); b23[ni][1] = rdB(p, ni + 2, 1); }
    WAIT_LGKM0;                 // all buf-p reads retired
    SB0; __builtin_amdgcn_s_barrier(); SB0;
    if (kt + 2 < 8) stage(kt + 2, p);
    __builtin_amdgcn_s_setprio(1);
#pragma unroll
    for (int mi = 0; mi < 2; ++mi)
#pragma unroll
      for (int ni = 0; ni < 2; ++ni) {
        acc[mi][ni + 2] = __builtin_amdgcn_mfma_f32_16x16x32_bf16(a[mi][0], b23[ni][0], acc[mi][ni + 2], 0, 0, 0);
        acc[mi][ni + 2] = __builtin_amdgcn_mfma_f32_16x16x32_bf16(a[mi][1], b23[ni][1], acc[mi][ni + 2], 0, 0, 0);
      }
    __builtin_amdgcn_s_setprio(0);
  }

  // ---- peeled last tile (kt=7, p=1): stores interleaved ----
  {
    const int p = 1;
    const int cc = lane & 15, cq = lane >> 4;
    WAIT_VM(0);
    SB0; __builtin_amdgcn_s_barrier(); SB0;

    float bv[4];
#pragma unroll
    for (int ni = 0; ni < 4; ++ni) bv[ni] = bias[bn0 + wn + ni * 16 + cc];

    auto st = [&](int mi, int ni) {
      const int gcol = bn0 + wn + ni * 16 + cc;
#pragma unroll
      for (int rr = 0; rr < 4; ++rr) {
        const int grow = bm0 + wm + mi * 16 + cq * 4 + rr;
        C[(size_t)grow * N + gcol] = acc[mi][ni][rr] + bv[ni];
      }
    };

    bf16x8 a[2][2], b01[2][2], b23[2][2];
#pragma unroll
    for (int mi = 0; mi < 2; ++mi) { a[mi][0] = rdA(p, mi, 0); a[mi][1] = rdA(p, mi, 1); }
#pragma unroll
    for (int ni = 0; ni < 2; ++ni) { b01[ni][0] = rdB(p, ni, 0); b01[ni][1] = rdB(p, ni, 1); }
    __builtin_amdgcn_s_setprio(1);
#pragma unroll
    for (int mi = 0; mi < 2; ++mi)
#pragma unroll
      for (int ni = 0; ni < 2; ++ni) {
        acc[mi][ni] = __builtin_amdgcn_mfma_f32_16x16x32_bf16(a[mi][0], b01[ni][0], acc[mi][ni], 0, 0, 0);
        acc[mi][ni] = __builtin_amdgcn_mfma_f32_16x16x32_bf16(a[mi][1], b01[ni][1], acc[mi][ni], 0, 0, 0);
      }
    __builtin_amdgcn_s_setprio(0);
#pragma unroll
    for (int mi = 0; mi < 2; ++mi)
#pragma unroll
      for (int ni = 0; ni < 2; ++ni) st(mi, ni);          // half 0 out

#pragma unroll
    for (int ni = 0; ni < 2; ++ni) { b23[ni][0] = rdB(p, ni + 2, 0); b23[ni][1] = rdB(p, ni + 2, 1); }
    __builtin_amdgcn_s_setprio(1);
#pragma unroll
    for (int mi = 0; mi < 2; ++mi)
#pragma unroll
      for (int ni = 0; ni < 2; ++ni) {
        acc[mi][ni + 2] = __builtin_amdgcn_mfma_f32_16x16x32_bf16(a[mi][0], b23[ni][0], acc[mi][ni + 2], 0, 0, 0);
        acc[mi][ni + 2] = __builtin_amdgcn_mfma_f32_16x16x32_bf16(a[mi][1], b23[ni][1], acc[mi][ni + 2], 0, 0, 0);
      }
    __builtin_amdgcn_s_setprio(0);
#pragma unroll
    for (int mi = 0; mi < 2; ++mi)
#pragma unroll
      for (int ni = 2; ni < 4; ++ni) st(mi, ni);          // half 1 out
  }
}

// Flash-style MFMA attention, QBLK=128 / 512 threads / 8 waves (r9 green).
__global__ __launch_bounds__(512) void attn_tile(
    const __bf16* __restrict__ qu,   // [B*L][2048]  q|k|v|u
    __bf16* __restrict__ g)          // [B*L][512]
{
  const int qt = blockIdx.x, h = blockIdx.y, b = blockIdx.z;
  const int t = threadIdx.x;
  const int lane = t & 63;
  const int w = t >> 6;                    // 8 waves, 16 q-rows each
  const int q0 = qt * 128, qmax = q0 + 127;
  const size_t bL = (size_t)b * L_;

  __shared__ __bf16 lK[4096];        // [64][64] bf16, XOR-swizzled rows (8KB)
  __shared__ __bf16 lV[64 * SP];     // V^T: [d 64][key 64] stride 72 (9KB)
  __shared__ __bf16 Pb[128 * SP];    // P: [q 128][key 64] stride 72 (18KB)

  const int cq = lane >> 4, cc = lane & 15;
  const int krow_st = t >> 3, kgb8 = t & 7;   // K-staging: 64 rows x 8 chunks

  // Q fragments, pre-scaled by 1/sqrt(HD)=0.125 (exact pow2 scale)
  bf16x8 aq0, aq1;
  {
    const __bf16* qsrc = qu + (bL + q0 + w * 16 + cc) * QS + h * 64 + cq * 8;
    bf16x8 t0 = *(const bf16x8*)qsrc;
    bf16x8 t1 = *(const bf16x8*)(qsrc + 32);
#pragma unroll
    for (int e = 0; e < 8; ++e) {
      aq0[e] = (__bf16)((float)t0[e] * 0.125f);
      aq1[e] = (__bf16)((float)t1[e] * 0.125f);
    }
  }

  float mreg[4], lreg[4];
#pragma unroll
  for (int rr = 0; rr < 4; ++rr) { mreg[rr] = -1e30f; lreg[rr] = 0.f; }
  f32x4 acc_o[4] = {};

  int clist[8]; int ncl = 0;
  clist[ncl++] = 0;
  if (qmax >= 64) clist[ncl++] = 64;
  {
    int lo = 1984 - qmax; if (lo < 0) lo = 0; lo &= ~63;
    const int hik = min(qmax, 2048 - q0);
    for (int c = lo; c <= hik; c += 64)
      if (c >= 128) clist[ncl++] = c;
  }

  // prologue: tile-0 K/V into registers (T14 pipeline)
  bf16x8 k0r, var;
  {
    const __bf16* src = qu + (bL + clist[0] + krow_st) * QS + 512 + h * 64;
    k0r = *(const bf16x8*)(src + kgb8 * 8);
    const __bf16* vsrc = qu + (bL + clist[0] + lane) * QS + 1024 + h * 64 + w * 8;
    var = *(const bf16x8*)vsrc;
  }

  for (int ci = 0; ci < ncl; ++ci) {
    const int c0 = clist[ci];
    // block-uniform tile classification
    const bool thin = (c0 == 64) && (qmax <= 1856);   // only col j=64 valid
    const bool fast0 = (c0 == 0) && (q0 >= 64) && (qmax + 63 <= 2048);

    WAIT_VM(0);                                 // this tile's K/V landed
    SB0; __builtin_amdgcn_s_barrier(); SB0;     // WAR: prior tile's reads done
    {
      char* lkb = (char*)lK;
      const int sw = (krow_st & 7) << 4;
      *(bf16x8*)(lkb + ((krow_st * 128 + kgb8 * 16) ^ sw)) = k0r;
#pragma unroll
      for (int e = 0; e < 8; ++e)
        lV[(w * 8 + e) * SP + lane] = var[e];
    }
    if (ci + 1 < ncl) {                         // issue next tile's loads
      const int cn = clist[ci + 1];
      const __bf16* src = qu + (bL + cn + krow_st) * QS + 512 + h * 64;
      k0r = *(const bf16x8*)(src + kgb8 * 8);
      const __bf16* vsrc = qu + (bL + cn + lane) * QS + 1024 + h * 64 + w * 8;
      var = *(const bf16x8*)vsrc;
    }
    WAIT_LGKM0;                                 // my ds_writes retired
    SB0; __builtin_amdgcn_s_barrier(); SB0;     // RAW: all writes visible

    // QK^T (nt=0 only on thin tiles)
    f32x4 s[4];
    {
      const char* lkb = (const char*)lK;
      auto qk = [&](int nt) {
        const int krow = nt * 16 + cc;
        const int sw = (krow & 7) << 4;
        bf16x8 bk0 = *(const bf16x8*)(lkb + ((krow * 128 + cq * 16) ^ sw));
        bf16x8 bk1 = *(const bf16x8*)(lkb + ((krow * 128 + 64 + cq * 16) ^ sw));
        f32x4 a = {};
        a = __builtin_amdgcn_mfma_f32_16x16x32_bf16(aq0, bk0, a, 0, 0, 0);
        a = __builtin_amdgcn_mfma_f32_16x16x32_bf16(aq1, bk1, a, 0, 0, 0);
        s[nt] = a;
      };
      qk(0);
      if (!thin) { qk(1); qk(2); qk(3); }
    }

    // mask (Q pre-scaled; no *0.125 here)
    if (!fast0) {
      const int ntm = thin ? 1 : 4;
      if (c0 >= 128) {
        // band-only mask: glob (j<=64) impossible here
        for (int nt = 0; nt < 4; ++nt) {
          if (nt >= ntm) break;
#pragma unroll
          for (int rr = 0; rr < 4; ++rr) {
            const int i = q0 + w * 16 + cq * 4 + rr;
            const int j = c0 + nt * 16 + cc;
            const int ij = i + j;
            const bool valid = (j <= i) && (ij >= 1984) && (ij <= 2048);
            s[nt][rr] = valid ? s[nt][rr] : -1e30f;
          }
        }
      } else {
        for (int nt = 0; nt < 4; ++nt) {
          if (nt >= ntm) break;
#pragma unroll
          for (int rr = 0; rr < 4; ++rr) {
            const int i = q0 + w * 16 + cq * 4 + rr;
            const int j = c0 + nt * 16 + cc;
            const int ij = i + j;
            const bool valid = (j <= i) &&
                ((ij >= 1984 && ij <= 2048) || (j <= 64 && ij <= 2048));
            s[nt][rr] = valid ? s[nt][rr] : -1e30f;
          }
        }
      }
    }

    // row max (in-lane over active nt, then 16-lane shfl tree)
    f32x4 pm;
#pragma unroll
    for (int rr = 0; rr < 4; ++rr) pm[rr] = s[0][rr];
    if (!thin) {
#pragma unroll
      for (int rr = 0; rr < 4; ++rr)
        pm[rr] = fmaxf(fmaxf(pm[rr], s[1][rr]), fmaxf(s[2][rr], s[3][rr]));
    }
#pragma unroll
    for (int m = 1; m < 16; m <<= 1) {
#pragma unroll
      for (int rr = 0; rr < 4; ++rr)
        pm[rr] = fmaxf(pm[rr], __shfl_xor(pm[rr], m, 64));
    }
    float corr[4];
#pragma unroll
    for (int rr = 0; rr < 4; ++rr) {
      const float nm = fmaxf(mreg[rr], pm[rr]);
      corr[rr] = __expf(mreg[rr] - nm);
      mreg[rr] = nm;
    }

    // P = exp(s - m); thin: write nt=0, zero slots 16..31 (PV k<=31 reads)
    f32x4 ps = {};
    if (thin) {
#pragma unroll
      for (int rr = 0; rr < 4; ++rr) {
        const float p = __expf(s[0][rr] - mreg[rr]);
        ps[rr] += p;
        const int prow = (w * 16 + cq * 4 + rr) * SP;
        Pb[prow + cc] = (__bf16)p;
        Pb[prow + 16 + cc] = (__bf16)0.f;
      }
    } else {
#pragma unroll
      for (int nt = 0; nt < 4; ++nt) {
#pragma unroll
        for (int rr = 0; rr < 4; ++rr) {
          const float p = __expf(s[nt][rr] - mreg[rr]);
          ps[rr] += p;
          Pb[(w * 16 + cq * 4 + rr) * SP + nt * 16 + cc] = (__bf16)p;
        }
      }
    }
#pragma unroll
    for (int m = 1; m < 16; m <<= 1) {
#pragma unroll
      for (int rr = 0; rr < 4; ++rr)
        ps[rr] += __shfl_xor(ps[rr], m, 64);
    }
#pragma unroll
    for (int rr = 0; rr < 4; ++rr) lreg[rr] = lreg[rr] * corr[rr] + ps[rr];

    // PV (thin: k=0..31 half only -> 4 MFMA)
    {
      bf16x8 pa0 = *(const bf16x8*)(Pb + (w * 16 + cc) * SP + cq * 8);
      if (thin) {
#pragma unroll
        for (int dt = 0; dt < 4; ++dt) {
#pragma unroll
          for (int rr = 0; rr < 4; ++rr) acc_o[dt][rr] *= corr[rr];
          bf16x8 vb0 = *(const bf16x8*)(lV + (dt * 16 + cc) * SP + cq * 8);
          acc_o[dt] = __builtin_amdgcn_mfma_f32_16x16x32_bf16(pa0, vb0, acc_o[dt], 0, 0, 0);
        }
      } else {
        bf16x8 pa1 = *(const bf16x8*)(Pb + (w * 16 + cc) * SP + 32 + cq * 8);
#pragma unroll
        for (int dt = 0; dt < 4; ++dt) {
#pragma unroll
          for (int rr = 0; rr < 4; ++rr) acc_o[dt][rr] *= corr[rr];
          bf16x8 vb0 = *(const bf16x8*)(lV + (dt * 16 + cc) * SP + cq * 8);
          bf16x8 vb1 = *(const bf16x8*)(lV + (dt * 16 + cc) * SP + 32 + cq * 8);
          acc_o[dt] = __builtin_amdgcn_mfma_f32_16x16x32_bf16(pa0, vb0, acc_o[dt], 0, 0, 0);
          acc_o[dt] = __builtin_amdgcn_mfma_f32_16x16x32_bf16(pa1, vb1, acc_o[dt], 0, 0, 0);
        }
      }
    }
  }

  // epilogue: register state only
#pragma unroll
  for (int dt = 0; dt < 4; ++dt) {
#pragma unroll
    for (int rr = 0; rr < 4; ++rr) {
      const int row16 = cq * 4 + rr;
      const size_t qrow = bL + q0 + w * 16 + row16;
      const int d = dt * 16 + cc;
      const float o = acc_o[dt][rr] / fmaxf(lreg[rr], 1e-30f);
      const float uv = (float)qu[qrow * QS + 1536 + h * 64 + d];
      g[qrow * D_ + h * 64 + d] = (__bf16)(o / (1.f + __expf(-o)) * uv);
    }
  }
}

extern "C" void kernel_launch(void* const* d_in, const int* in_sizes, int n_in,
                              void* d_out, int out_size, void* d_ws, size_t ws_size,
                              hipStream_t stream) {
  const float* x     = (const float*)d_in[0];
  const float* w_qkv = (const float*)d_in[1];
  const float* b_qkv = (const float*)d_in[2];
  const float* w_u   = (const float*)d_in[3];
  const float* b_u   = (const float*)d_in[4];
  const float* w_out = (const float*)d_in[5];
  const float* b_out = (const float*)d_in[6];
  float* out = (float*)d_out;

  char* ws = (char*)d_ws;
  __bf16* xb   = (__bf16*)ws;                           //  8 MB
  __bf16* wcat = (__bf16*)(ws + 8388608);               //  2 MB [w_qkv;w_u]
  __bf16* wob  = (__bf16*)(ws + 10485760);              //  0.5 MB
  float*  bcat = (float*) (ws + 11010048);              //  8 KB
  __bf16* qu   = (__bf16*)(ws + 11018240);              // 32 MB [q|k|v|u]
  __bf16* gb   = (__bf16*)(ws + 44572672);              //  8 MB

  // one-time opt-in for 64 KB dynamic LDS (host-side attr, graph-safe)
  static bool attr_done = []() {
    hipFuncSetAttribute((const void*)gemm128,
                        hipFuncAttributeMaxDynamicSharedMemorySize, 65536);
    return true;
  }();
  (void)attr_done;

  cvt_pack<<<dim3(2688), dim3(256), 0, stream>>>(
      x, w_qkv, w_u, w_out, b_qkv, b_u, xb, wcat, wob, bcat);
  gemm128<<<dim3(64, 16), dim3(256), 65536, stream>>>(
      xb, wcat, bcat, qu, 8192, 2048, 512);
  attn_tile<<<dim3(L_ / 128, H_, B_), dim3(512), 0, stream>>>(qu, gb);
  gemm_out<<<dim3(128, 4), dim3(256), 0, stream>>>(
      gb, wob, b_out, out);
}